// Round 3
// baseline (957.280 us; speedup 1.0000x reference)
//
#include <hip/hip_runtime.h>

#define NN 100000
#define NE 1600000
#define HID 64
#define EPSV 1e-5f
#define NB_ATT 1024

// ---------- small scratch layout (float indices into ws) ----------
#define SM_SUMS(l)  ((l)*128)
#define SM_SUMSQ(l) ((l)*128 + 64)
#define SM_HS       512
#define SM_C        576
#define SM_QS       640          // 128 floats
#define SM_HV       768          // 64 floats
#define SM_EOFF     832
#define SM_COUNT    1024

// big buffers (float offsets)
#define NPAD        100352L
#define OFF_DINV    1024L
#define OFF_H       (OFF_DINV + NPAD)       // 6.4M floats
#define OFF_Y32     (OFF_H + 6400000L)      // 3.2M uints (bf16x2)
#define OFF_PART    (OFF_Y32 + 3200000L)    // NB_ATT*68
#define OFF_INT     (OFF_PART + 69632L)
#define NSCAN1      391          // ceil(100000/256)

static __device__ __forceinline__ unsigned bf16rne(float f) {
  unsigned u = __float_as_uint(f);
  return (u + 0x7fffu + ((u >> 16) & 1u)) >> 16;
}
static __device__ __forceinline__ unsigned packbf2(float lo, float hi) {
  return bf16rne(lo) | (bf16rne(hi) << 16);
}
static __device__ __forceinline__ float bflo(unsigned w) { return __uint_as_float(w << 16); }
static __device__ __forceinline__ float bfhi(unsigned w) { return __uint_as_float(w & 0xffff0000u); }

// GraphNorm affine from accumulated sums: gn(x) = sc*x + sh  (per feature j)
static __device__ __forceinline__ void gn_affine(int j, const float* w, const float* b,
                                                 const float* ms, const float* sums,
                                                 const float* sumsq, float& sc, float& sh) {
  const float invn = 1.0f / (float)NN;
  float mean = sums[j] * invn;
  float ex2  = sumsq[j] * invn;
  float m    = ms[j];
  float var  = ex2 - m * mean * mean * (2.0f - m);
  sc = w[j] * rsqrtf(var + EPSV);
  sh = b[j] - sc * m * mean;
}

// ---------------- in-degree histogram (int), 1 edge/thread ----------------
__global__ __launch_bounds__(256) void k_deg(const int* __restrict__ dst, int* __restrict__ degi) {
  int e = blockIdx.x * 256 + threadIdx.x;   // grid sized exactly NE/256
  atomicAdd(&degi[dst[e]], 1);
}

// ---------------- 3-kernel exclusive scan over degi -> rowptr ----------------
__global__ __launch_bounds__(256) void k_scan1(const int* __restrict__ degi,
                                               int* __restrict__ excl, int* __restrict__ bsum) {
  __shared__ int ws[4];
  int t = threadIdx.x, lane = t & 63;
  int gid = blockIdx.x * 256 + t;
  int v = (gid < NN) ? degi[gid] : 0;
  int incl = v;
#pragma unroll
  for (int off = 1; off < 64; off <<= 1) {
    int u = __shfl_up(incl, off, 64);
    if (lane >= off) incl += u;
  }
  if (lane == 63) ws[t >> 6] = incl;
  __syncthreads();
  if (t == 0) {
    int s = 0;
#pragma unroll
    for (int w = 0; w < 4; ++w) { int tv = ws[w]; ws[w] = s; s += tv; }
    bsum[blockIdx.x] = s;
  }
  __syncthreads();
  if (gid < NN) excl[gid] = incl - v + ws[t >> 6];
}

__global__ __launch_bounds__(512) void k_scan2(int* __restrict__ bsum) {
  __shared__ int ws[8];
  int t = threadIdx.x, lane = t & 63;
  int v = (t < NSCAN1) ? bsum[t] : 0;
  int incl = v;
#pragma unroll
  for (int off = 1; off < 64; off <<= 1) {
    int u = __shfl_up(incl, off, 64);
    if (lane >= off) incl += u;
  }
  if (lane == 63) ws[t >> 6] = incl;
  __syncthreads();
  if (t == 0) {
    int s = 0;
#pragma unroll
    for (int w = 0; w < 8; ++w) { int tv = ws[w]; ws[w] = s; s += tv; }
  }
  __syncthreads();
  if (t < NSCAN1) bsum[t] = incl - v + ws[t >> 6];
}

__global__ __launch_bounds__(256) void k_scan3(int* __restrict__ rowptr, const int* __restrict__ bsum,
                                               const int* __restrict__ degi,
                                               int* __restrict__ cursor, float* __restrict__ dinv) {
  int t = threadIdx.x;
  int gid = blockIdx.x * 256 + t;
  if (gid < NN) {
    int r = rowptr[gid] + bsum[blockIdx.x];
    rowptr[gid] = r;
    cursor[gid] = r;
    dinv[gid] = rsqrtf((float)degi[gid] + 1.0f);
  }
  if (gid == 0) rowptr[NN] = NE;
}

// ---------------- CSR fill: col[pos] = src, grouped by dst (1 edge/thread) ----------------
__global__ __launch_bounds__(256) void k_fill(const int* __restrict__ src, const int* __restrict__ dst,
                                              int* __restrict__ cursor, int* __restrict__ col) {
  int e = blockIdx.x * 256 + threadIdx.x;   // grid sized exactly NE/256
  int d = dst[e];
  int pos = atomicAdd(&cursor[d], 1);
  col[pos] = src[e];
}

// ---------------- gn0 sums over x (D=4) ----------------
__global__ __launch_bounds__(256) void k_sums4(const float* __restrict__ x,
                                               float* __restrict__ sums, float* __restrict__ sumsq) {
  __shared__ float ls[256], lq[256];
  int t = threadIdx.x;
  float s = 0.f, q = 0.f;
  int stride = gridDim.x * blockDim.x;
  for (int idx = blockIdx.x * blockDim.x + t; idx < NN * 4; idx += stride) {
    float v = x[idx];
    s += v; q += v * v;
  }
  ls[t] = s; lq[t] = q;
  __syncthreads();
  if (t < 4) {
    float S = 0.f, Q = 0.f;
    for (int g = t; g < 256; g += 4) { S += ls[g]; Q += lq[g]; }
    atomicAdd(&sums[t], S);
    atomicAdd(&sumsq[t], Q);
  }
}

// ---------------- fused GraphNorm-apply + matmul + dinv prescale -> bf16 y ----------------
template <int D>
__global__ __launch_bounds__(256) void k_mm(const float* __restrict__ hin, const float* __restrict__ W,
                                            const float* __restrict__ gw, const float* __restrict__ gb,
                                            const float* __restrict__ gms,
                                            const float* __restrict__ sums, const float* __restrict__ sumsq,
                                            const float* __restrict__ dinv,
                                            unsigned* __restrict__ y32) {
  __shared__ float Ws[D][64];
  __shared__ float woff[64];
  __shared__ float scale[D], shift[D];
  __shared__ float hl[4][D];
  int t = threadIdx.x;
  if (t < D) {
    float sc, sh;
    gn_affine(t, gw, gb, gms, sums, sumsq, sc, sh);
    scale[t] = sc; shift[t] = sh;
  }
  __syncthreads();
  for (int idx = t; idx < D * 64; idx += 256) {
    int k = idx >> 6;
    Ws[k][idx & 63] = scale[k] * W[idx];
  }
  __syncthreads();
  if (t < 64) {
    float o = 0.f;
#pragma unroll
    for (int k = 0; k < D; ++k) o += shift[k] * W[k * 64 + t];
    woff[t] = o;
  }
  __syncthreads();

  int g = t >> 6, j = t & 63;
  const int nRG = NN / 4;  // 25000, exact
  for (int rg = blockIdx.x; rg < nRG; rg += gridDim.x) {
    int row = rg * 4 + g;
    if (D == 64) hl[g][j] = hin[row * 64 + j];
    else if (j < D) hl[g][j] = hin[row * D + j];
    __syncthreads();
    float a = woff[j];
#pragma unroll 16
    for (int k = 0; k < D; ++k) a += hl[g][k] * Ws[k][j];
    float val = dinv[row] * a;
    float vodd = __shfl_down(val, 1, 64);
    if ((j & 1) == 0) y32[row * 32 + (j >> 1)] = packbf2(val, vodd);
    __syncthreads();
  }
}

// ---------------- fused CSR gather (bf16, 2 edges/instr) + finalize ----------------
__global__ __launch_bounds__(256) void k_gather_fin(const unsigned* __restrict__ y32,
                                                    const int* __restrict__ rowptr, const int* __restrict__ col,
                                                    const float* __restrict__ dinv,
                                                    const float* __restrict__ b, const float* __restrict__ a,
                                                    float* __restrict__ h,
                                                    float* __restrict__ sums, float* __restrict__ sumsq) {
  __shared__ float ls0[4][32], ls1[4][32], lq0[4][32], lq1[4][32];
  int t = threadIdx.x, lane = t & 63, w = t >> 6;
  int half = lane >> 5, l31 = lane & 31;
  float b0 = b[2 * l31], b1 = b[2 * l31 + 1];
  bool pr = (a != nullptr);
  float a0 = pr ? a[2 * l31] : 1.f, a1 = pr ? a[2 * l31 + 1] : 1.f;
  float s0 = 0.f, s1 = 0.f, q0 = 0.f, q1 = 0.f;
  int nwaves = gridDim.x * 4;
  for (int i = blockIdx.x * 4 + w; i < NN; i += nwaves) {
    float f0 = 0.f, f1 = 0.f;
    int p1 = rowptr[i + 1];
    int p = rowptr[i];
    for (; p + 4 <= p1; p += 4) {
      unsigned wa = y32[col[p + half] * 32 + l31];
      unsigned wb = y32[col[p + 2 + half] * 32 + l31];
      f0 += bflo(wa) + bflo(wb);
      f1 += bfhi(wa) + bfhi(wb);
    }
    if (p + 2 <= p1) {
      unsigned wa = y32[col[p + half] * 32 + l31];
      f0 += bflo(wa); f1 += bfhi(wa);
      p += 2;
    }
    if (p < p1 && half == 0) {
      unsigned wa = y32[col[p] * 32 + l31];
      f0 += bflo(wa); f1 += bfhi(wa);
    }
    if (half == 0) {  // self-loop (dinv-prescaled)
      unsigned wself = y32[i * 32 + l31];
      f0 += bflo(wself); f1 += bfhi(wself);
    }
    f0 += __shfl_xor(f0, 32, 64);
    f1 += __shfl_xor(f1, 32, 64);
    if (half == 0) {
      float di = dinv[i];
      float v0 = di * f0 + b0, v1 = di * f1 + b1;
      if (pr) { if (v0 < 0.f) v0 *= a0; if (v1 < 0.f) v1 *= a1; }
      *(float2*)(h + i * 64 + 2 * l31) = make_float2(v0, v1);
      s0 += v0; s1 += v1; q0 += v0 * v0; q1 += v1 * v1;
    }
  }
  if ((lane >> 5) == 0) { ls0[w][l31] = s0; ls1[w][l31] = s1; lq0[w][l31] = q0; lq1[w][l31] = q1; }
  __syncthreads();
  if (t < 32) {
    float S0 = ls0[0][t] + ls0[1][t] + ls0[2][t] + ls0[3][t];
    float S1 = ls1[0][t] + ls1[1][t] + ls1[2][t] + ls1[3][t];
    float Q0 = lq0[0][t] + lq0[1][t] + lq0[2][t] + lq0[3][t];
    float Q1 = lq1[0][t] + lq1[1][t] + lq1[2][t] + lq1[3][t];
    atomicAdd(&sums[2 * t], S0);
    atomicAdd(&sums[2 * t + 1], S1);
    atomicAdd(&sumsq[2 * t], Q0);
    atomicAdd(&sumsq[2 * t + 1], Q1);
  }
}

// ---------------- Set2Set: fused attention pass (online softmax) ----------------
__global__ __launch_bounds__(256) void k_att(const float* __restrict__ h, const float* __restrict__ sm,
                                             float* __restrict__ part) {
  __shared__ float wm[4], wz[4], wr[4][64];
  int t = threadIdx.x, lane = t & 63, w = t >> 6;
  float hvl = sm[SM_HV + lane];
  float eoff = sm[SM_EOFF];
  float m = -3.4e38f, z = 0.f, r = 0.f;
  int nwaves = gridDim.x * 4;
  for (int i = blockIdx.x * 4 + w; i < NN; i += nwaves) {
    float hval = h[i * 64 + lane];
    float v = hval * hvl;
#pragma unroll
    for (int off = 32; off; off >>= 1) v += __shfl_xor(v, off, 64);
    float ei = v + eoff;
    if (ei > m) {
      float scl = expf(m - ei);
      z = z * scl + 1.f;
      r = r * scl + hval;
      m = ei;
    } else {
      float p = expf(ei - m);
      z += p;
      r += p * hval;
    }
  }
  wr[w][lane] = r;
  if (lane == 0) { wm[w] = m; wz[w] = z; }
  __syncthreads();
  if (t < 64) {
    float mb = fmaxf(fmaxf(wm[0], wm[1]), fmaxf(wm[2], wm[3]));
    float rb = 0.f, zb = 0.f;
#pragma unroll
    for (int k = 0; k < 4; ++k) {
      float scl = expf(wm[k] - mb);
      rb += wr[k][t] * scl;
      zb += wz[k] * scl;
    }
    part[blockIdx.x * 68 + t] = rb;
    if (t == 0) { part[blockIdx.x * 68 + 64] = mb; part[blockIdx.x * 68 + 65] = zb; }
  }
}

// ---------------- Set2Set finish: reduce partials -> q_star -> LSTM(next) -> hv ----------------
// mode 0: boot (no reduce; LSTM from q*=0), 1: mid step, 2: final (write out, no LSTM)
__global__ __launch_bounds__(256) void k_attfin(const float* __restrict__ part,
                                                const float* __restrict__ gw, const float* __restrict__ gb,
                                                const float* __restrict__ gms,
                                                const float* __restrict__ sums, const float* __restrict__ sumsq,
                                                const float* __restrict__ Wih, const float* __restrict__ Whh,
                                                const float* __restrict__ bih, const float* __restrict__ bhh,
                                                float* __restrict__ sm, float* __restrict__ out, int mode) {
  __shared__ float hsL[64], cL[64], qsL[128], gL[256], red[256], sf[NB_ATT];
  int t = threadIdx.x;
  if (t < 64) { hsL[t] = sm[SM_HS + t]; cL[t] = sm[SM_C + t]; }
  __syncthreads();
  if (mode > 0) {
    // global max over block partials
    float lm = -3.4e38f;
    for (int bk = t; bk < NB_ATT; bk += 256) lm = fmaxf(lm, part[bk * 68 + 64]);
    red[t] = lm; __syncthreads();
    for (int s = 128; s; s >>= 1) { if (t < s) red[t] = fmaxf(red[t], red[t + s]); __syncthreads(); }
    float mg = red[0];
    __syncthreads();
    // scale factors + z
    float lz = 0.f;
    for (int bk = t; bk < NB_ATT; bk += 256) {
      float scl = expf(part[bk * 68 + 64] - mg);
      sf[bk] = scl;
      lz += part[bk * 68 + 65] * scl;
    }
    red[t] = lz; __syncthreads();
    for (int s = 128; s; s >>= 1) { if (t < s) red[t] += red[t + s]; __syncthreads(); }
    float zg = red[0];
    __syncthreads();
    if (t < 64) {
      float rg = 0.f;
      for (int bk = 0; bk < NB_ATT; ++bk) rg += part[bk * 68 + t] * sf[bk];
      float sc, sh;
      gn_affine(t, gw, gb, gms, sums, sumsq, sc, sh);
      float rr = sc * (rg / zg) + sh;
      qsL[t] = hsL[t]; qsL[64 + t] = rr;
      if (mode == 2) { out[t] = hsL[t]; out[64 + t] = rr; }
    }
  } else {
    if (t < 64) { qsL[t] = 0.f; qsL[64 + t] = 0.f; hsL[t] = 0.f; cL[t] = 0.f; }
  }
  __syncthreads();
  if (mode == 2) return;
  // LSTM: one gate row per thread
  float g = bih[t] + bhh[t];
#pragma unroll 16
  for (int k = 0; k < 128; ++k) g += qsL[k] * Wih[t * 128 + k];
#pragma unroll 16
  for (int k = 0; k < 64; ++k) g += hsL[k] * Whh[t * 64 + k];
  gL[t] = g;
  __syncthreads();
  if (t < 64) {
    float ig = 1.f / (1.f + expf(-gL[t]));
    float fg = 1.f / (1.f + expf(-gL[64 + t]));
    float gg = tanhf(gL[128 + t]);
    float og = 1.f / (1.f + expf(-gL[192 + t]));
    float c = fg * cL[t] + ig * gg;
    float hsn = og * tanhf(c);
    sm[SM_C + t] = c;
    sm[SM_HS + t] = hsn;
    float sc, sh;
    gn_affine(t, gw, gb, gms, sums, sumsq, sc, sh);
    sm[SM_HV + t] = sc * hsn;
    red[t] = sh * hsn;
  }
  __syncthreads();
  if (t == 0) {
    float s = 0.f;
    for (int k = 0; k < 64; ++k) s += red[k];
    sm[SM_EOFF] = s;
  }
}

extern "C" void kernel_launch(void* const* d_in, const int* in_sizes, int n_in,
                              void* d_out, int out_size, void* d_ws, size_t ws_size,
                              hipStream_t stream) {
  const float* x     = (const float*)d_in[0];
  const float* gn0_w = (const float*)d_in[1];
  const float* gn0_b = (const float*)d_in[2];
  const float* gn0_ms= (const float*)d_in[3];
  const float* W1    = (const float*)d_in[4];
  const float* b1    = (const float*)d_in[5];
  const float* a1    = (const float*)d_in[6];
  const float* gn1_w = (const float*)d_in[7];
  const float* gn1_b = (const float*)d_in[8];
  const float* gn1_ms= (const float*)d_in[9];
  const float* W2    = (const float*)d_in[10];
  const float* b2    = (const float*)d_in[11];
  const float* a2    = (const float*)d_in[12];
  const float* gn2_w = (const float*)d_in[13];
  const float* gn2_b = (const float*)d_in[14];
  const float* gn2_ms= (const float*)d_in[15];
  const float* W3    = (const float*)d_in[16];
  const float* b3    = (const float*)d_in[17];
  const float* gn3_w = (const float*)d_in[18];
  const float* gn3_b = (const float*)d_in[19];
  const float* gn3_ms= (const float*)d_in[20];
  const float* Wih   = (const float*)d_in[21];
  const float* Whh   = (const float*)d_in[22];
  const float* bih   = (const float*)d_in[23];
  const float* bhh   = (const float*)d_in[24];
  const int*   eidx  = (const int*)d_in[25];
  const int* esrc = eidx;
  const int* edst = eidx + NE;

  float* sm   = (float*)d_ws;
  float* dinv = sm + OFF_DINV;
  float* h    = sm + OFF_H;
  unsigned* y32 = (unsigned*)(sm + OFF_Y32);
  float* part = sm + OFF_PART;
  int* degi   = (int*)(sm + OFF_INT);
  int* rowptr = degi + NPAD;          // NN+1
  int* cursor = rowptr + NPAD;
  int* col    = cursor + NPAD;        // NE
  int* bsum   = col + NE;             // NSCAN1
  float* out  = (float*)d_out;

  hipMemsetAsync(sm, 0, SM_COUNT * sizeof(float), stream);
  hipMemsetAsync(degi, 0, NN * sizeof(int), stream);

  // CSR build (once)
  k_deg<<<NE / 256, 256, 0, stream>>>(edst, degi);
  k_scan1<<<NSCAN1, 256, 0, stream>>>(degi, rowptr, bsum);
  k_scan2<<<1, 512, 0, stream>>>(bsum);
  k_scan3<<<NSCAN1, 256, 0, stream>>>(rowptr, bsum, degi, cursor, dinv);
  k_fill<<<NE / 256, 256, 0, stream>>>(esrc, edst, cursor, col);

  k_sums4<<<1024, 256, 0, stream>>>(x, sm + SM_SUMS(0), sm + SM_SUMSQ(0));

  // layer 1
  k_mm<4><<<2048, 256, 0, stream>>>(x, W1, gn0_w, gn0_b, gn0_ms,
                                    sm + SM_SUMS(0), sm + SM_SUMSQ(0), dinv, y32);
  k_gather_fin<<<2048, 256, 0, stream>>>(y32, rowptr, col, dinv, b1, a1, h,
                                         sm + SM_SUMS(1), sm + SM_SUMSQ(1));
  // layer 2
  k_mm<64><<<2048, 256, 0, stream>>>(h, W2, gn1_w, gn1_b, gn1_ms,
                                     sm + SM_SUMS(1), sm + SM_SUMSQ(1), dinv, y32);
  k_gather_fin<<<2048, 256, 0, stream>>>(y32, rowptr, col, dinv, b2, a2, h,
                                         sm + SM_SUMS(2), sm + SM_SUMSQ(2));
  // layer 3 (no prelu)
  k_mm<64><<<2048, 256, 0, stream>>>(h, W3, gn2_w, gn2_b, gn2_ms,
                                     sm + SM_SUMS(2), sm + SM_SUMSQ(2), dinv, y32);
  k_gather_fin<<<2048, 256, 0, stream>>>(y32, rowptr, col, dinv, b3, nullptr, h,
                                         sm + SM_SUMS(3), sm + SM_SUMSQ(3));

  // Set2Set: boot LSTM (q*=0) + hv, then 3 fused steps
  k_attfin<<<1, 256, 0, stream>>>(part, gn3_w, gn3_b, gn3_ms,
                                  sm + SM_SUMS(3), sm + SM_SUMSQ(3),
                                  Wih, Whh, bih, bhh, sm, nullptr, 0);
  for (int s = 0; s < 3; ++s) {
    k_att<<<NB_ATT, 256, 0, stream>>>(h, sm, part);
    k_attfin<<<1, 256, 0, stream>>>(part, gn3_w, gn3_b, gn3_ms,
                                    sm + SM_SUMS(3), sm + SM_SUMSQ(3),
                                    Wih, Whh, bih, bhh, sm,
                                    (s == 2) ? out : nullptr, (s == 2) ? 2 : 1);
  }
}

// Round 4
// 787.444 us; speedup vs baseline: 1.2157x; 1.2157x over previous
//
#include <hip/hip_runtime.h>

#define NN 100000
#define NE 1600000
#define HID 64
#define EPSV 1e-5f
#define NB_ATT 1024

// ---------- small scratch layout (float indices into ws) ----------
#define SM_SUMS(l)  ((l)*128)
#define SM_SUMSQ(l) ((l)*128 + 64)
#define SM_HS       512
#define SM_C        576
#define SM_QS       640          // 128 floats
#define SM_HV       768          // 64 floats
#define SM_EOFF     832
#define SM_COUNT    1024

// big buffers (float offsets)
#define NPAD        100352L
#define OFF_DINV    1024L
#define OFF_H       (OFF_DINV + NPAD)       // 6.4M floats
#define OFF_Y32     (OFF_H + 6400000L)      // 3.2M uints (bf16x2)
#define OFF_PART    (OFF_Y32 + 3200000L)    // NB_ATT*68
#define OFF_INT     (OFF_PART + 69632L)
#define NSCAN1      391          // ceil(100000/256)

static __device__ __forceinline__ unsigned bf16rne(float f) {
  unsigned u = __float_as_uint(f);
  return (u + 0x7fffu + ((u >> 16) & 1u)) >> 16;
}
static __device__ __forceinline__ unsigned packbf2(float lo, float hi) {
  return bf16rne(lo) | (bf16rne(hi) << 16);
}
static __device__ __forceinline__ float bflo(unsigned w) { return __uint_as_float(w << 16); }
static __device__ __forceinline__ float bfhi(unsigned w) { return __uint_as_float(w & 0xffff0000u); }

// GraphNorm affine from accumulated sums: gn(x) = sc*x + sh  (per feature j)
static __device__ __forceinline__ void gn_affine(int j, const float* w, const float* b,
                                                 const float* ms, const float* sums,
                                                 const float* sumsq, float& sc, float& sh) {
  const float invn = 1.0f / (float)NN;
  float mean = sums[j] * invn;
  float ex2  = sumsq[j] * invn;
  float m    = ms[j];
  float var  = ex2 - m * mean * mean * (2.0f - m);
  sc = w[j] * rsqrtf(var + EPSV);
  sh = b[j] - sc * m * mean;
}

// ---------------- in-degree histogram (int), 1 edge/thread ----------------
__global__ __launch_bounds__(256) void k_deg(const int* __restrict__ dst, int* __restrict__ degi) {
  int e = blockIdx.x * 256 + threadIdx.x;   // grid sized exactly NE/256
  atomicAdd(&degi[dst[e]], 1);
}

// ---------------- 3-kernel exclusive scan over degi -> rowptr ----------------
__global__ __launch_bounds__(256) void k_scan1(const int* __restrict__ degi,
                                               int* __restrict__ excl, int* __restrict__ bsum) {
  __shared__ int ws[4];
  int t = threadIdx.x, lane = t & 63;
  int gid = blockIdx.x * 256 + t;
  int v = (gid < NN) ? degi[gid] : 0;
  int incl = v;
#pragma unroll
  for (int off = 1; off < 64; off <<= 1) {
    int u = __shfl_up(incl, off, 64);
    if (lane >= off) incl += u;
  }
  if (lane == 63) ws[t >> 6] = incl;
  __syncthreads();
  if (t == 0) {
    int s = 0;
#pragma unroll
    for (int w = 0; w < 4; ++w) { int tv = ws[w]; ws[w] = s; s += tv; }
    bsum[blockIdx.x] = s;
  }
  __syncthreads();
  if (gid < NN) excl[gid] = incl - v + ws[t >> 6];
}

__global__ __launch_bounds__(512) void k_scan2(int* __restrict__ bsum) {
  __shared__ int ws[8];
  int t = threadIdx.x, lane = t & 63;
  int v = (t < NSCAN1) ? bsum[t] : 0;
  int incl = v;
#pragma unroll
  for (int off = 1; off < 64; off <<= 1) {
    int u = __shfl_up(incl, off, 64);
    if (lane >= off) incl += u;
  }
  if (lane == 63) ws[t >> 6] = incl;
  __syncthreads();
  if (t == 0) {
    int s = 0;
#pragma unroll
    for (int w = 0; w < 8; ++w) { int tv = ws[w]; ws[w] = s; s += tv; }
  }
  __syncthreads();
  if (t < NSCAN1) bsum[t] = incl - v + ws[t >> 6];
}

__global__ __launch_bounds__(256) void k_scan3(int* __restrict__ rowptr, const int* __restrict__ bsum,
                                               const int* __restrict__ degi,
                                               int* __restrict__ cursor, float* __restrict__ dinv) {
  int t = threadIdx.x;
  int gid = blockIdx.x * 256 + t;
  if (gid < NN) {
    int r = rowptr[gid] + bsum[blockIdx.x];
    rowptr[gid] = r;
    cursor[gid] = r;
    dinv[gid] = rsqrtf((float)degi[gid] + 1.0f);
  }
  if (gid == 0) rowptr[NN] = NE;
}

// ---------------- CSR fill: col[pos] = src, grouped by dst (1 edge/thread) ----------------
__global__ __launch_bounds__(256) void k_fill(const int* __restrict__ src, const int* __restrict__ dst,
                                              int* __restrict__ cursor, int* __restrict__ col) {
  int e = blockIdx.x * 256 + threadIdx.x;   // grid sized exactly NE/256
  int d = dst[e];
  int pos = atomicAdd(&cursor[d], 1);
  col[pos] = src[e];
}

// ---------------- gn0 sums over x (D=4) ----------------
__global__ __launch_bounds__(256) void k_sums4(const float* __restrict__ x,
                                               float* __restrict__ sums, float* __restrict__ sumsq) {
  __shared__ float ls[256], lq[256];
  int t = threadIdx.x;
  float s = 0.f, q = 0.f;
  int stride = gridDim.x * blockDim.x;
  for (int idx = blockIdx.x * blockDim.x + t; idx < NN * 4; idx += stride) {
    float v = x[idx];
    s += v; q += v * v;
  }
  ls[t] = s; lq[t] = q;
  __syncthreads();
  if (t < 4) {
    float S = 0.f, Q = 0.f;
    for (int g = t; g < 256; g += 4) { S += ls[g]; Q += lq[g]; }
    atomicAdd(&sums[t], S);
    atomicAdd(&sumsq[t], Q);
  }
}

// ---------------- fused GraphNorm-apply + matmul + dinv prescale -> bf16 y ----------------
template <int D>
__global__ __launch_bounds__(256) void k_mm(const float* __restrict__ hin, const float* __restrict__ W,
                                            const float* __restrict__ gw, const float* __restrict__ gb,
                                            const float* __restrict__ gms,
                                            const float* __restrict__ sums, const float* __restrict__ sumsq,
                                            const float* __restrict__ dinv,
                                            unsigned* __restrict__ y32) {
  __shared__ float Ws[D][64];
  __shared__ float woff[64];
  __shared__ float scale[D], shift[D];
  __shared__ float hl[4][D];
  int t = threadIdx.x;
  if (t < D) {
    float sc, sh;
    gn_affine(t, gw, gb, gms, sums, sumsq, sc, sh);
    scale[t] = sc; shift[t] = sh;
  }
  __syncthreads();
  for (int idx = t; idx < D * 64; idx += 256) {
    int k = idx >> 6;
    Ws[k][idx & 63] = scale[k] * W[idx];
  }
  __syncthreads();
  if (t < 64) {
    float o = 0.f;
#pragma unroll
    for (int k = 0; k < D; ++k) o += shift[k] * W[k * 64 + t];
    woff[t] = o;
  }
  __syncthreads();

  int g = t >> 6, j = t & 63;
  const int nRG = NN / 4;  // 25000, exact
  for (int rg = blockIdx.x; rg < nRG; rg += gridDim.x) {
    int row = rg * 4 + g;
    if (D == 64) hl[g][j] = hin[row * 64 + j];
    else if (j < D) hl[g][j] = hin[row * D + j];
    __syncthreads();
    float a = woff[j];
#pragma unroll 16
    for (int k = 0; k < D; ++k) a += hl[g][k] * Ws[k][j];
    float val = dinv[row] * a;
    float vodd = __shfl_down(val, 1, 64);
    if ((j & 1) == 0) y32[row * 32 + (j >> 1)] = packbf2(val, vodd);
    __syncthreads();
  }
}

// ---------------- fused CSR gather (bf16, octet layout: 8 edges / wave-instr) ----------------
#define ACC4(W) { f[0]+=bflo(W.x); f[1]+=bfhi(W.x); f[2]+=bflo(W.y); f[3]+=bfhi(W.y); \
                  f[4]+=bflo(W.z); f[5]+=bfhi(W.z); f[6]+=bflo(W.w); f[7]+=bfhi(W.w); }

template <bool PR>
__global__ __launch_bounds__(256) void k_gather_fin(const uint4* __restrict__ y4,
                                                    const int* __restrict__ rowptr, const int* __restrict__ col,
                                                    const float* __restrict__ dinv,
                                                    const float* __restrict__ b, const float* __restrict__ a,
                                                    float* __restrict__ h,
                                                    float* __restrict__ sums, float* __restrict__ sumsq) {
  __shared__ float lsum[4][64], lsq[4][64];
  int t = threadIdx.x, lane = t & 63, w = t >> 6;
  int o = lane >> 3, l7 = lane & 7;      // octet o handles edge group o; lane covers feats 8*l7..+7
  float bv[8], av[8];
#pragma unroll
  for (int k = 0; k < 8; ++k) {
    bv[k] = b[8 * l7 + k];
    av[k] = PR ? a[8 * l7 + k] : 1.f;
  }
  float sa[8] = {0,0,0,0,0,0,0,0}, qa[8] = {0,0,0,0,0,0,0,0};
  int nwaves = gridDim.x * 4;
  for (int i = blockIdx.x * 4 + w; i < NN; i += nwaves) {
    float f[8] = {0,0,0,0,0,0,0,0};
    int p = rowptr[i], p1 = rowptr[i + 1];
    // main: 16 edges/iter, 2 independent 8-row uint4 loads (2 KB in flight)
    for (; p + 16 <= p1; p += 16) {
      int c0 = col[p + o], c1 = col[p + 8 + o];
      uint4 wa = y4[c0 * 8 + l7];
      uint4 wb = y4[c1 * 8 + l7];
      ACC4(wa); ACC4(wb);
    }
    if (p + 8 <= p1) {
      int c0 = col[p + o];
      uint4 wa = y4[c0 * 8 + l7];
      ACC4(wa);
      p += 8;
    }
    // tail (<8 edges) + self-loop in one predicated octet round
    {
      int r = p1 - p;                     // 0..7
      int c = (o < r) ? col[p + o] : ((o == r) ? i : -1);
      if (c >= 0) {
        uint4 wa = y4[c * 8 + l7];
        ACC4(wa);
      }
    }
    // reduce across octets (bits 3..5 of lane)
#pragma unroll
    for (int k = 0; k < 8; ++k) {
      float v = f[k];
      v += __shfl_xor(v, 8, 64);
      v += __shfl_xor(v, 16, 64);
      v += __shfl_xor(v, 32, 64);
      f[k] = v;
    }
    float di = dinv[i];
    float vo[8];
#pragma unroll
    for (int k = 0; k < 8; ++k) {
      float v = di * f[k] + bv[k];
      if (PR && v < 0.f) v *= av[k];
      vo[k] = v;
      sa[k] += v; qa[k] += v * v;
    }
    if (o == 0) {
      *(float4*)(h + (long)i * 64 + 8 * l7)     = make_float4(vo[0], vo[1], vo[2], vo[3]);
      *(float4*)(h + (long)i * 64 + 8 * l7 + 4) = make_float4(vo[4], vo[5], vo[6], vo[7]);
    }
  }
  if (o == 0) {
#pragma unroll
    for (int k = 0; k < 8; ++k) { lsum[w][8 * l7 + k] = sa[k]; lsq[w][8 * l7 + k] = qa[k]; }
  }
  __syncthreads();
  if (t < 64) {
    float S = lsum[0][t] + lsum[1][t] + lsum[2][t] + lsum[3][t];
    float Q = lsq[0][t] + lsq[1][t] + lsq[2][t] + lsq[3][t];
    atomicAdd(&sums[t], S);
    atomicAdd(&sumsq[t], Q);
  }
}

// ---------------- Set2Set: fused attention pass (online softmax) ----------------
__global__ __launch_bounds__(256) void k_att(const float* __restrict__ h, const float* __restrict__ sm,
                                             float* __restrict__ part) {
  __shared__ float wm[4], wz[4], wr[4][64];
  int t = threadIdx.x, lane = t & 63, w = t >> 6;
  float hvl = sm[SM_HV + lane];
  float eoff = sm[SM_EOFF];
  float m = -3.4e38f, z = 0.f, r = 0.f;
  int nwaves = gridDim.x * 4;
  for (int i = blockIdx.x * 4 + w; i < NN; i += nwaves) {
    float hval = h[i * 64 + lane];
    float v = hval * hvl;
#pragma unroll
    for (int off = 32; off; off >>= 1) v += __shfl_xor(v, off, 64);
    float ei = v + eoff;
    if (ei > m) {
      float scl = expf(m - ei);
      z = z * scl + 1.f;
      r = r * scl + hval;
      m = ei;
    } else {
      float p = expf(ei - m);
      z += p;
      r += p * hval;
    }
  }
  wr[w][lane] = r;
  if (lane == 0) { wm[w] = m; wz[w] = z; }
  __syncthreads();
  if (t < 64) {
    float mb = fmaxf(fmaxf(wm[0], wm[1]), fmaxf(wm[2], wm[3]));
    float rb = 0.f, zb = 0.f;
#pragma unroll
    for (int k = 0; k < 4; ++k) {
      float scl = expf(wm[k] - mb);
      rb += wr[k][t] * scl;
      zb += wz[k] * scl;
    }
    part[blockIdx.x * 68 + t] = rb;
    if (t == 0) { part[blockIdx.x * 68 + 64] = mb; part[blockIdx.x * 68 + 65] = zb; }
  }
}

// ---------------- Set2Set finish: reduce partials -> q_star -> LSTM(next) -> hv ----------------
// mode 0: boot (no reduce; LSTM from q*=0), 1: mid step, 2: final (write out, no LSTM)
__global__ __launch_bounds__(256) void k_attfin(const float* __restrict__ part,
                                                const float* __restrict__ gw, const float* __restrict__ gb,
                                                const float* __restrict__ gms,
                                                const float* __restrict__ sums, const float* __restrict__ sumsq,
                                                const float* __restrict__ Wih, const float* __restrict__ Whh,
                                                const float* __restrict__ bih, const float* __restrict__ bhh,
                                                float* __restrict__ sm, float* __restrict__ out, int mode) {
  __shared__ float hsL[64], cL[64], qsL[128], gL[256], red[256], sf[NB_ATT];
  int t = threadIdx.x;
  if (t < 64) { hsL[t] = sm[SM_HS + t]; cL[t] = sm[SM_C + t]; }
  __syncthreads();
  if (mode > 0) {
    float lm = -3.4e38f;
    for (int bk = t; bk < NB_ATT; bk += 256) lm = fmaxf(lm, part[bk * 68 + 64]);
    red[t] = lm; __syncthreads();
    for (int s = 128; s; s >>= 1) { if (t < s) red[t] = fmaxf(red[t], red[t + s]); __syncthreads(); }
    float mg = red[0];
    __syncthreads();
    float lz = 0.f;
    for (int bk = t; bk < NB_ATT; bk += 256) {
      float scl = expf(part[bk * 68 + 64] - mg);
      sf[bk] = scl;
      lz += part[bk * 68 + 65] * scl;
    }
    red[t] = lz; __syncthreads();
    for (int s = 128; s; s >>= 1) { if (t < s) red[t] += red[t + s]; __syncthreads(); }
    float zg = red[0];
    __syncthreads();
    if (t < 64) {
      float rg = 0.f;
      for (int bk = 0; bk < NB_ATT; ++bk) rg += part[bk * 68 + t] * sf[bk];
      float sc, sh;
      gn_affine(t, gw, gb, gms, sums, sumsq, sc, sh);
      float rr = sc * (rg / zg) + sh;
      qsL[t] = hsL[t]; qsL[64 + t] = rr;
      if (mode == 2) { out[t] = hsL[t]; out[64 + t] = rr; }
    }
  } else {
    if (t < 64) { qsL[t] = 0.f; qsL[64 + t] = 0.f; hsL[t] = 0.f; cL[t] = 0.f; }
  }
  __syncthreads();
  if (mode == 2) return;
  float g = bih[t] + bhh[t];
#pragma unroll 16
  for (int k = 0; k < 128; ++k) g += qsL[k] * Wih[t * 128 + k];
#pragma unroll 16
  for (int k = 0; k < 64; ++k) g += hsL[k] * Whh[t * 64 + k];
  gL[t] = g;
  __syncthreads();
  if (t < 64) {
    float ig = 1.f / (1.f + expf(-gL[t]));
    float fg = 1.f / (1.f + expf(-gL[64 + t]));
    float gg = tanhf(gL[128 + t]);
    float og = 1.f / (1.f + expf(-gL[192 + t]));
    float c = fg * cL[t] + ig * gg;
    float hsn = og * tanhf(c);
    sm[SM_C + t] = c;
    sm[SM_HS + t] = hsn;
    float sc, sh;
    gn_affine(t, gw, gb, gms, sums, sumsq, sc, sh);
    sm[SM_HV + t] = sc * hsn;
    red[t] = sh * hsn;
  }
  __syncthreads();
  if (t == 0) {
    float s = 0.f;
    for (int k = 0; k < 64; ++k) s += red[k];
    sm[SM_EOFF] = s;
  }
}

extern "C" void kernel_launch(void* const* d_in, const int* in_sizes, int n_in,
                              void* d_out, int out_size, void* d_ws, size_t ws_size,
                              hipStream_t stream) {
  const float* x     = (const float*)d_in[0];
  const float* gn0_w = (const float*)d_in[1];
  const float* gn0_b = (const float*)d_in[2];
  const float* gn0_ms= (const float*)d_in[3];
  const float* W1    = (const float*)d_in[4];
  const float* b1    = (const float*)d_in[5];
  const float* a1    = (const float*)d_in[6];
  const float* gn1_w = (const float*)d_in[7];
  const float* gn1_b = (const float*)d_in[8];
  const float* gn1_ms= (const float*)d_in[9];
  const float* W2    = (const float*)d_in[10];
  const float* b2    = (const float*)d_in[11];
  const float* a2    = (const float*)d_in[12];
  const float* gn2_w = (const float*)d_in[13];
  const float* gn2_b = (const float*)d_in[14];
  const float* gn2_ms= (const float*)d_in[15];
  const float* W3    = (const float*)d_in[16];
  const float* b3    = (const float*)d_in[17];
  const float* gn3_w = (const float*)d_in[18];
  const float* gn3_b = (const float*)d_in[19];
  const float* gn3_ms= (const float*)d_in[20];
  const float* Wih   = (const float*)d_in[21];
  const float* Whh   = (const float*)d_in[22];
  const float* bih   = (const float*)d_in[23];
  const float* bhh   = (const float*)d_in[24];
  const int*   eidx  = (const int*)d_in[25];
  const int* esrc = eidx;
  const int* edst = eidx + NE;

  float* sm   = (float*)d_ws;
  float* dinv = sm + OFF_DINV;
  float* h    = sm + OFF_H;
  unsigned* y32 = (unsigned*)(sm + OFF_Y32);
  const uint4* y4 = (const uint4*)y32;
  float* part = sm + OFF_PART;
  int* degi   = (int*)(sm + OFF_INT);
  int* rowptr = degi + NPAD;          // NN+1
  int* cursor = rowptr + NPAD;
  int* col    = cursor + NPAD;        // NE
  int* bsum   = col + NE;             // NSCAN1
  float* out  = (float*)d_out;

  hipMemsetAsync(sm, 0, SM_COUNT * sizeof(float), stream);
  hipMemsetAsync(degi, 0, NN * sizeof(int), stream);

  // CSR build (once)
  k_deg<<<NE / 256, 256, 0, stream>>>(edst, degi);
  k_scan1<<<NSCAN1, 256, 0, stream>>>(degi, rowptr, bsum);
  k_scan2<<<1, 512, 0, stream>>>(bsum);
  k_scan3<<<NSCAN1, 256, 0, stream>>>(rowptr, bsum, degi, cursor, dinv);
  k_fill<<<NE / 256, 256, 0, stream>>>(esrc, edst, cursor, col);

  k_sums4<<<1024, 256, 0, stream>>>(x, sm + SM_SUMS(0), sm + SM_SUMSQ(0));

  // layer 1
  k_mm<4><<<2048, 256, 0, stream>>>(x, W1, gn0_w, gn0_b, gn0_ms,
                                    sm + SM_SUMS(0), sm + SM_SUMSQ(0), dinv, y32);
  k_gather_fin<true><<<2048, 256, 0, stream>>>(y4, rowptr, col, dinv, b1, a1, h,
                                               sm + SM_SUMS(1), sm + SM_SUMSQ(1));
  // layer 2
  k_mm<64><<<2048, 256, 0, stream>>>(h, W2, gn1_w, gn1_b, gn1_ms,
                                     sm + SM_SUMS(1), sm + SM_SUMSQ(1), dinv, y32);
  k_gather_fin<true><<<2048, 256, 0, stream>>>(y4, rowptr, col, dinv, b2, a2, h,
                                               sm + SM_SUMS(2), sm + SM_SUMSQ(2));
  // layer 3 (no prelu)
  k_mm<64><<<2048, 256, 0, stream>>>(h, W3, gn2_w, gn2_b, gn2_ms,
                                     sm + SM_SUMS(2), sm + SM_SUMSQ(2), dinv, y32);
  k_gather_fin<false><<<2048, 256, 0, stream>>>(y4, rowptr, col, dinv, b3, nullptr, h,
                                                sm + SM_SUMS(3), sm + SM_SUMSQ(3));

  // Set2Set: boot LSTM (q*=0) + hv, then 3 fused steps
  k_attfin<<<1, 256, 0, stream>>>(part, gn3_w, gn3_b, gn3_ms,
                                  sm + SM_SUMS(3), sm + SM_SUMSQ(3),
                                  Wih, Whh, bih, bhh, sm, nullptr, 0);
  for (int s = 0; s < 3; ++s) {
    k_att<<<NB_ATT, 256, 0, stream>>>(h, sm, part);
    k_attfin<<<1, 256, 0, stream>>>(part, gn3_w, gn3_b, gn3_ms,
                                    sm + SM_SUMS(3), sm + SM_SUMSQ(3),
                                    Wih, Whh, bih, bhh, sm,
                                    (s == 2) ? out : nullptr, (s == 2) ? 2 : 1);
  }
}

// Round 5
// 606.534 us; speedup vs baseline: 1.5783x; 1.2983x over previous
//
#include <hip/hip_runtime.h>

#define NN 100000
#define NE 1600000
#define HID 64
#define EPSV 1e-5f
#define NB_ATT 1024

// bucketed CSR build
#define NBUK 391                 // ceil(NN/256), bucket = dst>>8
#define BCAP 4608                // slots per bucket (lambda=4096, +8 sigma)
#define BTILE 4096               // edges per k_bin block
#define NTILES 391               // ceil(NE/BTILE)

// ---------- small scratch layout (float indices into ws) ----------
#define SM_SUMS(l)  ((l)*128)
#define SM_SUMSQ(l) ((l)*128 + 64)
#define SM_HS       512
#define SM_C        576
#define SM_HV       768          // 64 floats
#define SM_EOFF     832
#define SM_COUNT    1024

// big buffers (float offsets)
#define NPAD        100352L
#define OFF_DINV    1024L
#define OFF_H       (OFF_DINV + NPAD)       // 6.4M floats; stage aliases its head
#define OFF_Y32     (OFF_H + 6400000L)      // 3.2M uints (bf16x2)
#define OFF_PART    (OFF_Y32 + 3200000L)    // NB_ATT*68
#define OFF_INT     (OFF_PART + 69632L)

static __device__ __forceinline__ unsigned bf16rne(float f) {
  unsigned u = __float_as_uint(f);
  return (u + 0x7fffu + ((u >> 16) & 1u)) >> 16;
}
static __device__ __forceinline__ unsigned packbf2(float lo, float hi) {
  return bf16rne(lo) | (bf16rne(hi) << 16);
}
static __device__ __forceinline__ float bflo(unsigned w) { return __uint_as_float(w << 16); }
static __device__ __forceinline__ float bfhi(unsigned w) { return __uint_as_float(w & 0xffff0000u); }

// GraphNorm affine from accumulated sums: gn(x) = sc*x + sh  (per feature j)
static __device__ __forceinline__ void gn_affine(int j, const float* w, const float* b,
                                                 const float* ms, const float* sums,
                                                 const float* sumsq, float& sc, float& sh) {
  const float invn = 1.0f / (float)NN;
  float mean = sums[j] * invn;
  float ex2  = sumsq[j] * invn;
  float m    = ms[j];
  float var  = ex2 - m * mean * mean * (2.0f - m);
  sc = w[j] * rsqrtf(var + EPSV);
  sh = b[j] - sc * m * mean;
}

// ---------------- bucket cursor init ----------------
__global__ __launch_bounds__(512) void k_binit(int* __restrict__ gcursor) {
  int t = threadIdx.x;
  if (t < NBUK) gcursor[t] = t * BCAP;
}

// ---------------- pass 1: bin edges into per-bucket staging ----------------
// stage entry: (local_dst & 255) << 24 | src   (src < 2^17)
__global__ __launch_bounds__(256) void k_bin(const int* __restrict__ src, const int* __restrict__ dst,
                                             int* __restrict__ gcursor, unsigned* __restrict__ stage) {
  __shared__ int hist[NBUK], base[NBUK];
  int t = threadIdx.x;
  long tile0 = (long)blockIdx.x * BTILE;
  for (int b = t; b < NBUK; b += 256) hist[b] = 0;
  __syncthreads();
  unsigned v[16]; int bk[16];
#pragma unroll
  for (int k = 0; k < 16; ++k) {
    long e = tile0 + k * 256 + t;
    if (e < NE) {
      int d = dst[e], s = src[e];
      bk[k] = d >> 8;
      v[k] = ((unsigned)(d & 255) << 24) | (unsigned)s;
      atomicAdd(&hist[bk[k]], 1);
    } else bk[k] = -1;
  }
  __syncthreads();
  for (int b = t; b < NBUK; b += 256) {
    int c = hist[b];
    base[b] = c ? atomicAdd(&gcursor[b], c) : 0;
    hist[b] = 0;
  }
  __syncthreads();
#pragma unroll
  for (int k = 0; k < 16; ++k) {
    if (bk[k] >= 0) {
      int off = atomicAdd(&hist[bk[k]], 1);
      stage[base[bk[k]] + off] = v[k];
    }
  }
}

// ---------------- pass 1b: scan bucket counts -> boff ----------------
__global__ __launch_bounds__(512) void k_bscan(const int* __restrict__ gcursor,
                                               int* __restrict__ boff, int* __restrict__ rowptr) {
  __shared__ int ws[8];
  int t = threadIdx.x, lane = t & 63;
  int c = (t < NBUK) ? (gcursor[t] - t * BCAP) : 0;
  int incl = c;
#pragma unroll
  for (int off = 1; off < 64; off <<= 1) {
    int u = __shfl_up(incl, off, 64);
    if (lane >= off) incl += u;
  }
  if (lane == 63) ws[t >> 6] = incl;
  __syncthreads();
  if (t == 0) {
    int s = 0;
#pragma unroll
    for (int w = 0; w < 8; ++w) { int tv = ws[w]; ws[w] = s; s += tv; }
  }
  __syncthreads();
  if (t < NBUK) boff[t] = incl - c + ws[t >> 6];
  if (t == 0) { boff[NBUK] = NE; rowptr[NN] = NE; }
}

// ---------------- pass 2: per-bucket counting sort -> col, rowptr, dinv ----------------
__global__ __launch_bounds__(256) void k_bsort(const unsigned* __restrict__ stage,
                                               const int* __restrict__ boff,
                                               int* __restrict__ col, int* __restrict__ rowptr,
                                               float* __restrict__ dinv) {
  __shared__ int hist[256], cur[256];
  __shared__ int ws[4];
  int b = blockIdx.x;
  int t = threadIdx.x, lane = t & 63;
  int sb = b * BCAP;
  int b0 = boff[b], cb = boff[b + 1] - b0;
  hist[t] = 0;
  __syncthreads();
  for (int j = t; j < cb; j += 256)
    atomicAdd(&hist[stage[sb + j] >> 24], 1);
  __syncthreads();
  int c = hist[t];
  int incl = c;
#pragma unroll
  for (int off = 1; off < 64; off <<= 1) {
    int u = __shfl_up(incl, off, 64);
    if (lane >= off) incl += u;
  }
  if (lane == 63) ws[t >> 6] = incl;
  __syncthreads();
  int woff = 0;
  if (t >= 64) woff += ws[0];
  if (t >= 128) woff += ws[1];
  if (t >= 192) woff += ws[2];
  int gbase = b0 + (incl - c) + woff;
  int node = b * 256 + t;
  if (node < NN) {
    rowptr[node] = gbase;
    dinv[node] = rsqrtf((float)c + 1.0f);
  }
  cur[t] = gbase;
  __syncthreads();
  for (int j = t; j < cb; j += 256) {
    unsigned v = stage[sb + j];
    int pos = atomicAdd(&cur[v >> 24], 1);
    col[pos] = (int)(v & 0xffffffu);
  }
}

// ---------------- gn0 sums over x (D=4) ----------------
__global__ __launch_bounds__(256) void k_sums4(const float* __restrict__ x,
                                               float* __restrict__ sums, float* __restrict__ sumsq) {
  __shared__ float ls[256], lq[256];
  int t = threadIdx.x;
  float s = 0.f, q = 0.f;
  int stride = gridDim.x * blockDim.x;
  for (int idx = blockIdx.x * blockDim.x + t; idx < NN * 4; idx += stride) {
    float v = x[idx];
    s += v; q += v * v;
  }
  ls[t] = s; lq[t] = q;
  __syncthreads();
  if (t < 4) {
    float S = 0.f, Q = 0.f;
    for (int g = t; g < 256; g += 4) { S += ls[g]; Q += lq[g]; }
    atomicAdd(&sums[t], S);
    atomicAdd(&sumsq[t], Q);
  }
}

// ---------------- fused GraphNorm-apply + matmul + dinv prescale -> bf16 y ----------------
template <int D>
__global__ __launch_bounds__(256) void k_mm(const float* __restrict__ hin, const float* __restrict__ W,
                                            const float* __restrict__ gw, const float* __restrict__ gb,
                                            const float* __restrict__ gms,
                                            const float* __restrict__ sums, const float* __restrict__ sumsq,
                                            const float* __restrict__ dinv,
                                            unsigned* __restrict__ y32) {
  __shared__ float Ws[D][64];
  __shared__ float woff[64];
  __shared__ float scale[D], shift[D];
  __shared__ float hl[4][D];
  int t = threadIdx.x;
  if (t < D) {
    float sc, sh;
    gn_affine(t, gw, gb, gms, sums, sumsq, sc, sh);
    scale[t] = sc; shift[t] = sh;
  }
  __syncthreads();
  for (int idx = t; idx < D * 64; idx += 256) {
    int k = idx >> 6;
    Ws[k][idx & 63] = scale[k] * W[idx];
  }
  __syncthreads();
  if (t < 64) {
    float o = 0.f;
#pragma unroll
    for (int k = 0; k < D; ++k) o += shift[k] * W[k * 64 + t];
    woff[t] = o;
  }
  __syncthreads();

  int g = t >> 6, j = t & 63;
  const int nRG = NN / 4;  // 25000, exact
  for (int rg = blockIdx.x; rg < nRG; rg += gridDim.x) {
    int row = rg * 4 + g;
    if (D == 64) hl[g][j] = hin[row * 64 + j];
    else if (j < D) hl[g][j] = hin[row * D + j];
    __syncthreads();
    float a = woff[j];
#pragma unroll 16
    for (int k = 0; k < D; ++k) a += hl[g][k] * Ws[k][j];
    float val = dinv[row] * a;
    float vodd = __shfl_down(val, 1, 64);
    if ((j & 1) == 0) y32[row * 32 + (j >> 1)] = packbf2(val, vodd);
    __syncthreads();
  }
}

// ---------------- fused CSR gather (bf16, octet layout: 8 edges / wave-instr) ----------------
#define ACC4(W) { f[0]+=bflo(W.x); f[1]+=bfhi(W.x); f[2]+=bflo(W.y); f[3]+=bfhi(W.y); \
                  f[4]+=bflo(W.z); f[5]+=bfhi(W.z); f[6]+=bflo(W.w); f[7]+=bfhi(W.w); }

template <bool PR>
__global__ __launch_bounds__(256) void k_gather_fin(const uint4* __restrict__ y4,
                                                    const int* __restrict__ rowptr, const int* __restrict__ col,
                                                    const float* __restrict__ dinv,
                                                    const float* __restrict__ b, const float* __restrict__ a,
                                                    float* __restrict__ h,
                                                    float* __restrict__ sums, float* __restrict__ sumsq) {
  __shared__ float lsum[4][64], lsq[4][64];
  int t = threadIdx.x, lane = t & 63, w = t >> 6;
  int o = lane >> 3, l7 = lane & 7;
  float bv[8], av[8];
#pragma unroll
  for (int k = 0; k < 8; ++k) {
    bv[k] = b[8 * l7 + k];
    av[k] = PR ? a[8 * l7 + k] : 1.f;
  }
  float sa[8] = {0,0,0,0,0,0,0,0}, qa[8] = {0,0,0,0,0,0,0,0};
  int nwaves = gridDim.x * 4;
  for (int i = blockIdx.x * 4 + w; i < NN; i += nwaves) {
    float f[8] = {0,0,0,0,0,0,0,0};
    int p = rowptr[i], p1 = rowptr[i + 1];
    for (; p + 16 <= p1; p += 16) {
      int c0 = col[p + o], c1 = col[p + 8 + o];
      uint4 wa = y4[c0 * 8 + l7];
      uint4 wb = y4[c1 * 8 + l7];
      ACC4(wa); ACC4(wb);
    }
    if (p + 8 <= p1) {
      int c0 = col[p + o];
      uint4 wa = y4[c0 * 8 + l7];
      ACC4(wa);
      p += 8;
    }
    {
      int r = p1 - p;                     // 0..7
      int c = (o < r) ? col[p + o] : ((o == r) ? i : -1);
      if (c >= 0) {
        uint4 wa = y4[c * 8 + l7];
        ACC4(wa);
      }
    }
#pragma unroll
    for (int k = 0; k < 8; ++k) {
      float v = f[k];
      v += __shfl_xor(v, 8, 64);
      v += __shfl_xor(v, 16, 64);
      v += __shfl_xor(v, 32, 64);
      f[k] = v;
    }
    float di = dinv[i];
    float vo[8];
#pragma unroll
    for (int k = 0; k < 8; ++k) {
      float v = di * f[k] + bv[k];
      if (PR && v < 0.f) v *= av[k];
      vo[k] = v;
      sa[k] += v; qa[k] += v * v;
    }
    if (o == 0) {
      *(float4*)(h + (long)i * 64 + 8 * l7)     = make_float4(vo[0], vo[1], vo[2], vo[3]);
      *(float4*)(h + (long)i * 64 + 8 * l7 + 4) = make_float4(vo[4], vo[5], vo[6], vo[7]);
    }
  }
  if (o == 0) {
#pragma unroll
    for (int k = 0; k < 8; ++k) { lsum[w][8 * l7 + k] = sa[k]; lsq[w][8 * l7 + k] = qa[k]; }
  }
  __syncthreads();
  if (t < 64) {
    float S = lsum[0][t] + lsum[1][t] + lsum[2][t] + lsum[3][t];
    float Q = lsq[0][t] + lsq[1][t] + lsq[2][t] + lsq[3][t];
    atomicAdd(&sums[t], S);
    atomicAdd(&sumsq[t], Q);
  }
}

// ---------------- Set2Set: fused attention pass (16-lane groups, float4) ----------------
__global__ __launch_bounds__(256) void k_att(const float* __restrict__ h, const float* __restrict__ sm,
                                             float* __restrict__ part) {
  __shared__ float gm[16], gz[16], gr[16][64];
  int t = threadIdx.x;
  int grp = t >> 4, fl = t & 15;
  float4 hv4 = *(const float4*)(sm + SM_HV + 4 * fl);
  float eoff = sm[SM_EOFF];
  float m = -3.4e38f, z = 0.f;
  float4 r = make_float4(0.f, 0.f, 0.f, 0.f);
  int ngrp = gridDim.x * 16;
  for (int i = blockIdx.x * 16 + grp; i < NN; i += ngrp) {
    float4 hv_ = *(const float4*)(h + (long)i * 64 + 4 * fl);
    float dot = hv_.x * hv4.x + hv_.y * hv4.y + hv_.z * hv4.z + hv_.w * hv4.w;
    dot += __shfl_xor(dot, 1, 64);
    dot += __shfl_xor(dot, 2, 64);
    dot += __shfl_xor(dot, 4, 64);
    dot += __shfl_xor(dot, 8, 64);
    float e = dot + eoff;
    float mn = fmaxf(m, e);
    float sa = expf(m - mn);     // 1 when m==mn
    float pb = expf(e - mn);
    z = z * sa + pb;
    r.x = r.x * sa + pb * hv_.x;
    r.y = r.y * sa + pb * hv_.y;
    r.z = r.z * sa + pb * hv_.z;
    r.w = r.w * sa + pb * hv_.w;
    m = mn;
  }
  *(float4*)(&gr[grp][4 * fl]) = r;
  if (fl == 0) { gm[grp] = m; gz[grp] = z; }
  __syncthreads();
  if (t < 64) {
    float mb = gm[0];
#pragma unroll
    for (int k = 1; k < 16; ++k) mb = fmaxf(mb, gm[k]);
    float rb = 0.f, zb = 0.f;
#pragma unroll
    for (int k = 0; k < 16; ++k) {
      float scl = expf(gm[k] - mb);
      rb += gr[k][t] * scl;
      zb += gz[k] * scl;
    }
    part[blockIdx.x * 68 + t] = rb;
    if (t == 0) { part[blockIdx.x * 68 + 64] = mb; part[blockIdx.x * 68 + 65] = zb; }
  }
}

// ---------------- Set2Set finish: reduce partials -> q_star -> LSTM(next) -> hv ----------------
// mode 0: boot (no reduce; LSTM from q*=0), 1: mid step, 2: final (write out, no LSTM)
__global__ __launch_bounds__(256) void k_attfin(const float* __restrict__ part,
                                                const float* __restrict__ gw, const float* __restrict__ gb,
                                                const float* __restrict__ gms,
                                                const float* __restrict__ sums, const float* __restrict__ sumsq,
                                                const float* __restrict__ Wih, const float* __restrict__ Whh,
                                                const float* __restrict__ bih, const float* __restrict__ bhh,
                                                float* __restrict__ sm, float* __restrict__ out, int mode) {
  __shared__ float hsL[64], cL[64], qsL[128], gL[256], red[256], sf[NB_ATT];
  int t = threadIdx.x;
  if (t < 64) { hsL[t] = sm[SM_HS + t]; cL[t] = sm[SM_C + t]; }
  __syncthreads();
  if (mode > 0) {
    float lm = -3.4e38f;
    for (int bk = t; bk < NB_ATT; bk += 256) lm = fmaxf(lm, part[bk * 68 + 64]);
    red[t] = lm; __syncthreads();
    for (int s = 128; s; s >>= 1) { if (t < s) red[t] = fmaxf(red[t], red[t + s]); __syncthreads(); }
    float mg = red[0];
    __syncthreads();
    float lz = 0.f;
    for (int bk = t; bk < NB_ATT; bk += 256) {
      float scl = expf(part[bk * 68 + 64] - mg);
      sf[bk] = scl;
      lz += part[bk * 68 + 65] * scl;
    }
    red[t] = lz; __syncthreads();
    for (int s = 128; s; s >>= 1) { if (t < s) red[t] += red[t + s]; __syncthreads(); }
    float zg = red[0];
    __syncthreads();
    if (t < 64) {
      float rg = 0.f;
      for (int bk = 0; bk < NB_ATT; ++bk) rg += part[bk * 68 + t] * sf[bk];
      float sc, sh;
      gn_affine(t, gw, gb, gms, sums, sumsq, sc, sh);
      float rr = sc * (rg / zg) + sh;
      qsL[t] = hsL[t]; qsL[64 + t] = rr;
      if (mode == 2) { out[t] = hsL[t]; out[64 + t] = rr; }
    }
  } else {
    if (t < 64) { qsL[t] = 0.f; qsL[64 + t] = 0.f; hsL[t] = 0.f; cL[t] = 0.f; }
  }
  __syncthreads();
  if (mode == 2) return;
  float g = bih[t] + bhh[t];
#pragma unroll 16
  for (int k = 0; k < 128; ++k) g += qsL[k] * Wih[t * 128 + k];
#pragma unroll 16
  for (int k = 0; k < 64; ++k) g += hsL[k] * Whh[t * 64 + k];
  gL[t] = g;
  __syncthreads();
  if (t < 64) {
    float ig = 1.f / (1.f + expf(-gL[t]));
    float fg = 1.f / (1.f + expf(-gL[64 + t]));
    float gg = tanhf(gL[128 + t]);
    float og = 1.f / (1.f + expf(-gL[192 + t]));
    float c = fg * cL[t] + ig * gg;
    float hsn = og * tanhf(c);
    sm[SM_C + t] = c;
    sm[SM_HS + t] = hsn;
    float sc, sh;
    gn_affine(t, gw, gb, gms, sums, sumsq, sc, sh);
    sm[SM_HV + t] = sc * hsn;
    red[t] = sh * hsn;
  }
  __syncthreads();
  if (t == 0) {
    float s = 0.f;
    for (int k = 0; k < 64; ++k) s += red[k];
    sm[SM_EOFF] = s;
  }
}

extern "C" void kernel_launch(void* const* d_in, const int* in_sizes, int n_in,
                              void* d_out, int out_size, void* d_ws, size_t ws_size,
                              hipStream_t stream) {
  const float* x     = (const float*)d_in[0];
  const float* gn0_w = (const float*)d_in[1];
  const float* gn0_b = (const float*)d_in[2];
  const float* gn0_ms= (const float*)d_in[3];
  const float* W1    = (const float*)d_in[4];
  const float* b1    = (const float*)d_in[5];
  const float* a1    = (const float*)d_in[6];
  const float* gn1_w = (const float*)d_in[7];
  const float* gn1_b = (const float*)d_in[8];
  const float* gn1_ms= (const float*)d_in[9];
  const float* W2    = (const float*)d_in[10];
  const float* b2    = (const float*)d_in[11];
  const float* a2    = (const float*)d_in[12];
  const float* gn2_w = (const float*)d_in[13];
  const float* gn2_b = (const float*)d_in[14];
  const float* gn2_ms= (const float*)d_in[15];
  const float* W3    = (const float*)d_in[16];
  const float* b3    = (const float*)d_in[17];
  const float* gn3_w = (const float*)d_in[18];
  const float* gn3_b = (const float*)d_in[19];
  const float* gn3_ms= (const float*)d_in[20];
  const float* Wih   = (const float*)d_in[21];
  const float* Whh   = (const float*)d_in[22];
  const float* bih   = (const float*)d_in[23];
  const float* bhh   = (const float*)d_in[24];
  const int*   eidx  = (const int*)d_in[25];
  const int* esrc = eidx;
  const int* edst = eidx + NE;

  float* sm   = (float*)d_ws;
  float* dinv = sm + OFF_DINV;
  float* h    = sm + OFF_H;
  unsigned* stage = (unsigned*)(sm + OFF_H);   // aliases h head; dead before first gather
  unsigned* y32 = (unsigned*)(sm + OFF_Y32);
  const uint4* y4 = (const uint4*)y32;
  float* part = sm + OFF_PART;
  int* col    = (int*)(sm + OFF_INT);          // NE
  int* rowptr = col + NE;                      // NPAD (NN+1)
  int* gcursor= rowptr + NPAD;                 // NBUK
  int* boff   = gcursor + 512;                 // NBUK+1
  float* out  = (float*)d_out;

  hipMemsetAsync(sm, 0, SM_COUNT * sizeof(float), stream);

  // CSR build via bucketed counting sort (once)
  k_binit<<<1, 512, 0, stream>>>(gcursor);
  k_bin<<<NTILES, 256, 0, stream>>>(esrc, edst, gcursor, stage);
  k_bscan<<<1, 512, 0, stream>>>(gcursor, boff, rowptr);
  k_bsort<<<NBUK, 256, 0, stream>>>(stage, boff, col, rowptr, dinv);

  k_sums4<<<1024, 256, 0, stream>>>(x, sm + SM_SUMS(0), sm + SM_SUMSQ(0));

  // layer 1
  k_mm<4><<<2048, 256, 0, stream>>>(x, W1, gn0_w, gn0_b, gn0_ms,
                                    sm + SM_SUMS(0), sm + SM_SUMSQ(0), dinv, y32);
  k_gather_fin<true><<<2048, 256, 0, stream>>>(y4, rowptr, col, dinv, b1, a1, h,
                                               sm + SM_SUMS(1), sm + SM_SUMSQ(1));
  // layer 2
  k_mm<64><<<2048, 256, 0, stream>>>(h, W2, gn1_w, gn1_b, gn1_ms,
                                     sm + SM_SUMS(1), sm + SM_SUMSQ(1), dinv, y32);
  k_gather_fin<true><<<2048, 256, 0, stream>>>(y4, rowptr, col, dinv, b2, a2, h,
                                               sm + SM_SUMS(2), sm + SM_SUMSQ(2));
  // layer 3 (no prelu)
  k_mm<64><<<2048, 256, 0, stream>>>(h, W3, gn2_w, gn2_b, gn2_ms,
                                     sm + SM_SUMS(2), sm + SM_SUMSQ(2), dinv, y32);
  k_gather_fin<false><<<2048, 256, 0, stream>>>(y4, rowptr, col, dinv, b3, nullptr, h,
                                                sm + SM_SUMS(3), sm + SM_SUMSQ(3));

  // Set2Set: boot LSTM (q*=0) + hv, then 3 fused steps
  k_attfin<<<1, 256, 0, stream>>>(part, gn3_w, gn3_b, gn3_ms,
                                  sm + SM_SUMS(3), sm + SM_SUMSQ(3),
                                  Wih, Whh, bih, bhh, sm, nullptr, 0);
  for (int s = 0; s < 3; ++s) {
    k_att<<<NB_ATT, 256, 0, stream>>>(h, sm, part);
    k_attfin<<<1, 256, 0, stream>>>(part, gn3_w, gn3_b, gn3_ms,
                                    sm + SM_SUMS(3), sm + SM_SUMSQ(3),
                                    Wih, Whh, bih, bhh, sm,
                                    (s == 2) ? out : nullptr, (s == 2) ? 2 : 1);
  }
}

// Round 6
// 455.809 us; speedup vs baseline: 2.1002x; 1.3307x over previous
//
#include <hip/hip_runtime.h>

#define NN 100000
#define NE 1600000
#define HID 64
#define EPSV 1e-5f
#define NB_ATT 256

// bucketed CSR build
#define NBUK 391                 // ceil(NN/256), bucket = dst>>8
#define BCAP 4608                // slots per bucket (lambda=4096, +8 sigma)
#define BTILE 4096               // edges per k_bin block
#define NTILES 391               // ceil(NE/BTILE)

// ---------- small scratch layout (float indices into ws) ----------
#define SM_SUMS(l)  ((l)*128)
#define SM_SUMSQ(l) ((l)*128 + 64)
#define SM_HS       512
#define SM_C        576
#define SM_HV       768          // 64 floats
#define SM_EOFF     832
#define SM_COUNT    1024

// big buffers (float offsets)
#define NPAD        100352L
#define OFF_DINV    1024L
#define OFF_H       (OFF_DINV + NPAD)       // 6.4M floats; stage AND hb alias this region
#define OFF_Y32     (OFF_H + 6400000L)      // 3.2M uints (bf16x2)
#define OFF_PART    (OFF_Y32 + 3200000L)    // NB_ATT*68
#define OFF_INT     (OFF_PART + 69632L)

static __device__ __forceinline__ unsigned bf16rne(float f) {
  unsigned u = __float_as_uint(f);
  return (u + 0x7fffu + ((u >> 16) & 1u)) >> 16;
}
static __device__ __forceinline__ unsigned packbf2(float lo, float hi) {
  return bf16rne(lo) | (bf16rne(hi) << 16);
}
static __device__ __forceinline__ float bflo(unsigned w) { return __uint_as_float(w << 16); }
static __device__ __forceinline__ float bfhi(unsigned w) { return __uint_as_float(w & 0xffff0000u); }

// GraphNorm affine from accumulated sums: gn(x) = sc*x + sh  (per feature j)
static __device__ __forceinline__ void gn_affine(int j, const float* w, const float* b,
                                                 const float* ms, const float* sums,
                                                 const float* sumsq, float& sc, float& sh) {
  const float invn = 1.0f / (float)NN;
  float mean = sums[j] * invn;
  float ex2  = sumsq[j] * invn;
  float m    = ms[j];
  float var  = ex2 - m * mean * mean * (2.0f - m);
  sc = w[j] * rsqrtf(var + EPSV);
  sh = b[j] - sc * m * mean;
}

// ---------------- bucket cursor init ----------------
__global__ __launch_bounds__(512) void k_binit(int* __restrict__ gcursor) {
  int t = threadIdx.x;
  if (t < NBUK) gcursor[t] = t * BCAP;
}

// ---------------- pass 1: bin edges into per-bucket staging ----------------
// stage entry: (local_dst & 255) << 24 | src   (src < 2^17)
__global__ __launch_bounds__(256) void k_bin(const int* __restrict__ src, const int* __restrict__ dst,
                                             int* __restrict__ gcursor, unsigned* __restrict__ stage) {
  __shared__ int hist[NBUK], base[NBUK];
  int t = threadIdx.x;
  long tile0 = (long)blockIdx.x * BTILE;
  for (int b = t; b < NBUK; b += 256) hist[b] = 0;
  __syncthreads();
  unsigned v[16]; int bk[16];
#pragma unroll
  for (int k = 0; k < 16; ++k) {
    long e = tile0 + k * 256 + t;
    if (e < NE) {
      int d = dst[e], s = src[e];
      bk[k] = d >> 8;
      v[k] = ((unsigned)(d & 255) << 24) | (unsigned)s;
      atomicAdd(&hist[bk[k]], 1);
    } else bk[k] = -1;
  }
  __syncthreads();
  for (int b = t; b < NBUK; b += 256) {
    int c = hist[b];
    base[b] = c ? atomicAdd(&gcursor[b], c) : 0;
    hist[b] = 0;
  }
  __syncthreads();
#pragma unroll
  for (int k = 0; k < 16; ++k) {
    if (bk[k] >= 0) {
      int off = atomicAdd(&hist[bk[k]], 1);
      stage[base[bk[k]] + off] = v[k];
    }
  }
}

// ---------------- pass 1b: scan bucket counts -> boff ----------------
__global__ __launch_bounds__(512) void k_bscan(const int* __restrict__ gcursor,
                                               int* __restrict__ boff, int* __restrict__ rowptr) {
  __shared__ int ws[8];
  int t = threadIdx.x, lane = t & 63;
  int c = (t < NBUK) ? (gcursor[t] - t * BCAP) : 0;
  int incl = c;
#pragma unroll
  for (int off = 1; off < 64; off <<= 1) {
    int u = __shfl_up(incl, off, 64);
    if (lane >= off) incl += u;
  }
  if (lane == 63) ws[t >> 6] = incl;
  __syncthreads();
  if (t == 0) {
    int s = 0;
#pragma unroll
    for (int w = 0; w < 8; ++w) { int tv = ws[w]; ws[w] = s; s += tv; }
  }
  __syncthreads();
  if (t < NBUK) boff[t] = incl - c + ws[t >> 6];
  if (t == 0) { boff[NBUK] = NE; rowptr[NN] = NE; }
}

// ---------------- pass 2: per-bucket counting sort -> col, rowptr, dinv ----------------
__global__ __launch_bounds__(256) void k_bsort(const unsigned* __restrict__ stage,
                                               const int* __restrict__ boff,
                                               int* __restrict__ col, int* __restrict__ rowptr,
                                               float* __restrict__ dinv) {
  __shared__ int hist[256], cur[256];
  __shared__ int ws[4];
  int b = blockIdx.x;
  int t = threadIdx.x, lane = t & 63;
  int sb = b * BCAP;
  int b0 = boff[b], cb = boff[b + 1] - b0;
  hist[t] = 0;
  __syncthreads();
  for (int j = t; j < cb; j += 256)
    atomicAdd(&hist[stage[sb + j] >> 24], 1);
  __syncthreads();
  int c = hist[t];
  int incl = c;
#pragma unroll
  for (int off = 1; off < 64; off <<= 1) {
    int u = __shfl_up(incl, off, 64);
    if (lane >= off) incl += u;
  }
  if (lane == 63) ws[t >> 6] = incl;
  __syncthreads();
  int woff = 0;
  if (t >= 64) woff += ws[0];
  if (t >= 128) woff += ws[1];
  if (t >= 192) woff += ws[2];
  int gbase = b0 + (incl - c) + woff;
  int node = b * 256 + t;
  if (node < NN) {
    rowptr[node] = gbase;
    dinv[node] = rsqrtf((float)c + 1.0f);
  }
  cur[t] = gbase;
  __syncthreads();
  for (int j = t; j < cb; j += 256) {
    unsigned v = stage[sb + j];
    int pos = atomicAdd(&cur[v >> 24], 1);
    col[pos] = (int)(v & 0xffffffu);
  }
}

// ---------------- gn0 sums over x (D=4) ----------------
__global__ __launch_bounds__(256) void k_sums4(const float* __restrict__ x,
                                               float* __restrict__ sums, float* __restrict__ sumsq) {
  __shared__ float ls[256], lq[256];
  int t = threadIdx.x;
  float s = 0.f, q = 0.f;
  int stride = gridDim.x * blockDim.x;
  for (int idx = blockIdx.x * blockDim.x + t; idx < NN * 4; idx += stride) {
    float v = x[idx];
    s += v; q += v * v;
  }
  ls[t] = s; lq[t] = q;
  __syncthreads();
  if (t < 4) {
    float S = 0.f, Q = 0.f;
    for (int g = t; g < 256; g += 4) { S += ls[g]; Q += lq[g]; }
    atomicAdd(&sums[t], S);
    atomicAdd(&sumsq[t], Q);
  }
}

// ---------------- fused GraphNorm-apply + matmul + dinv prescale -> bf16 y ----------------
// 16 rows per iteration, float4 staging, float4 W reads, 4 cols per thread.
template <int D>
__global__ __launch_bounds__(256) void k_mm(const float* __restrict__ hin, const float* __restrict__ W,
                                            const float* __restrict__ gw, const float* __restrict__ gb,
                                            const float* __restrict__ gms,
                                            const float* __restrict__ sums, const float* __restrict__ sumsq,
                                            const float* __restrict__ dinv,
                                            unsigned* __restrict__ y32) {
  __shared__ float4 Ws4[D][16];
  __shared__ float4 woff4[16];
  __shared__ float scale[D], shift[D];
  __shared__ float hl[16][68];      // stride 68: 16B-aligned rows, bank-shift 4
  int t = threadIdx.x;
  if (t < D) {
    float sc, sh;
    gn_affine(t, gw, gb, gms, sums, sumsq, sc, sh);
    scale[t] = sc; shift[t] = sh;
  }
  __syncthreads();
  for (int idx = t; idx < D * 64; idx += 256) {
    int k = idx >> 6;
    ((float*)Ws4)[idx] = scale[k] * W[idx];
  }
  __syncthreads();
  if (t < 64) {
    float o = 0.f;
#pragma unroll
    for (int k = 0; k < D; ++k) o += shift[k] * W[k * 64 + t];
    ((float*)woff4)[t] = o;
  }
  __syncthreads();

  int row = t >> 4, cg = t & 15;
  const int nG = NN / 16;  // 6250, exact
  for (int g = blockIdx.x; g < nG; g += gridDim.x) {
    if (D == 64) {
      *(float4*)&hl[row][cg * 4] = *(const float4*)(hin + (long)(g * 16 + row) * 64 + cg * 4);
    } else {
      if (t < 64) hl[t >> 2][t & 3] = hin[g * 64 + t];
    }
    __syncthreads();
    float4 acc = woff4[cg];
#pragma unroll
    for (int k = 0; k < D; ++k) {
      float hk = hl[row][k];
      float4 w4 = Ws4[k][cg];
      acc.x += hk * w4.x; acc.y += hk * w4.y;
      acc.z += hk * w4.z; acc.w += hk * w4.w;
    }
    int node = g * 16 + row;
    float di = dinv[node];
    uint2 u;
    u.x = packbf2(di * acc.x, di * acc.y);
    u.y = packbf2(di * acc.z, di * acc.w);
    *(uint2*)(y32 + (long)node * 32 + 2 * cg) = u;
    __syncthreads();
  }
}

// ---------------- fused CSR gather (bf16, octet layout: 8 edges / wave-instr) ----------------
#define ACC4(W) { f[0]+=bflo(W.x); f[1]+=bfhi(W.x); f[2]+=bflo(W.y); f[3]+=bfhi(W.y); \
                  f[4]+=bflo(W.z); f[5]+=bfhi(W.z); f[6]+=bflo(W.w); f[7]+=bfhi(W.w); }

// PR: apply prelu; HB: write bf16 h copy (no fp32 h write)
template <bool PR, bool HB>
__global__ __launch_bounds__(256) void k_gather_fin(const uint4* __restrict__ y4,
                                                    const int* __restrict__ rowptr, const int* __restrict__ col,
                                                    const float* __restrict__ dinv,
                                                    const float* __restrict__ b, const float* __restrict__ a,
                                                    float* __restrict__ h, uint4* __restrict__ hb4,
                                                    float* __restrict__ sums, float* __restrict__ sumsq) {
  __shared__ float lsum[4][64], lsq[4][64];
  int t = threadIdx.x, lane = t & 63, w = t >> 6;
  int o = lane >> 3, l7 = lane & 7;
  float bv[8], av[8];
#pragma unroll
  for (int k = 0; k < 8; ++k) {
    bv[k] = b[8 * l7 + k];
    av[k] = PR ? a[8 * l7 + k] : 1.f;
  }
  float sa[8] = {0,0,0,0,0,0,0,0}, qa[8] = {0,0,0,0,0,0,0,0};
  int nwaves = gridDim.x * 4;
  for (int i = blockIdx.x * 4 + w; i < NN; i += nwaves) {
    float f[8] = {0,0,0,0,0,0,0,0};
    int p = rowptr[i], p1 = rowptr[i + 1];
    for (; p + 16 <= p1; p += 16) {
      int c0 = col[p + o], c1 = col[p + 8 + o];
      uint4 wa = y4[c0 * 8 + l7];
      uint4 wb = y4[c1 * 8 + l7];
      ACC4(wa); ACC4(wb);
    }
    if (p + 8 <= p1) {
      int c0 = col[p + o];
      uint4 wa = y4[c0 * 8 + l7];
      ACC4(wa);
      p += 8;
    }
    {
      int r = p1 - p;                     // 0..7
      int c = (o < r) ? col[p + o] : ((o == r) ? i : -1);
      if (c >= 0) {
        uint4 wa = y4[c * 8 + l7];
        ACC4(wa);
      }
    }
#pragma unroll
    for (int k = 0; k < 8; ++k) {
      float v = f[k];
      v += __shfl_xor(v, 8, 64);
      v += __shfl_xor(v, 16, 64);
      v += __shfl_xor(v, 32, 64);
      f[k] = v;
    }
    float di = dinv[i];
    float vo[8];
#pragma unroll
    for (int k = 0; k < 8; ++k) {
      float v = di * f[k] + bv[k];
      if (PR && v < 0.f) v *= av[k];
      vo[k] = v;
      sa[k] += v; qa[k] += v * v;
    }
    if (o == 0) {
      if (HB) {
        uint4 u;
        u.x = packbf2(vo[0], vo[1]); u.y = packbf2(vo[2], vo[3]);
        u.z = packbf2(vo[4], vo[5]); u.w = packbf2(vo[6], vo[7]);
        hb4[(long)i * 8 + l7] = u;
      } else {
        *(float4*)(h + (long)i * 64 + 8 * l7)     = make_float4(vo[0], vo[1], vo[2], vo[3]);
        *(float4*)(h + (long)i * 64 + 8 * l7 + 4) = make_float4(vo[4], vo[5], vo[6], vo[7]);
      }
    }
  }
  if (o == 0) {
#pragma unroll
    for (int k = 0; k < 8; ++k) { lsum[w][8 * l7 + k] = sa[k]; lsq[w][8 * l7 + k] = qa[k]; }
  }
  __syncthreads();
  if (t < 64) {
    float S = lsum[0][t] + lsum[1][t] + lsum[2][t] + lsum[3][t];
    float Q = lsq[0][t] + lsq[1][t] + lsq[2][t] + lsq[3][t];
    atomicAdd(&sums[t], S);
    atomicAdd(&sumsq[t], Q);
  }
}

// ---------------- Set2Set: fused attention pass (bf16 h, 8-lane groups) ----------------
__global__ __launch_bounds__(256) void k_att(const uint4* __restrict__ hb4, const float* __restrict__ sm,
                                             float* __restrict__ part) {
  __shared__ float gm[32], gz[32], gr[32][64];
  int t = threadIdx.x;
  int grp = t >> 3, l7 = t & 7;
  float hvr[8];
#pragma unroll
  for (int k = 0; k < 8; ++k) hvr[k] = sm[SM_HV + 8 * l7 + k];
  float eoff = sm[SM_EOFF];
  float m = -3.4e38f, z = 0.f;
  float r[8] = {0,0,0,0,0,0,0,0};
  int ngrp = gridDim.x * 32;
  for (int i = blockIdx.x * 32 + grp; i < NN; i += ngrp) {
    uint4 hw = hb4[(long)i * 8 + l7];
    float hx[8] = { bflo(hw.x), bfhi(hw.x), bflo(hw.y), bfhi(hw.y),
                    bflo(hw.z), bfhi(hw.z), bflo(hw.w), bfhi(hw.w) };
    float dot = 0.f;
#pragma unroll
    for (int k = 0; k < 8; ++k) dot += hx[k] * hvr[k];
    dot += __shfl_xor(dot, 1, 64);
    dot += __shfl_xor(dot, 2, 64);
    dot += __shfl_xor(dot, 4, 64);
    float e = dot + eoff;
    float mn = fmaxf(m, e);
    float sa = expf(m - mn);
    float pb = expf(e - mn);
    z = z * sa + pb;
#pragma unroll
    for (int k = 0; k < 8; ++k) r[k] = r[k] * sa + pb * hx[k];
    m = mn;
  }
#pragma unroll
  for (int k = 0; k < 8; ++k) gr[grp][8 * l7 + k] = r[k];
  if (l7 == 0) { gm[grp] = m; gz[grp] = z; }
  __syncthreads();
  if (t < 64) {
    float mb = gm[0];
#pragma unroll
    for (int k = 1; k < 32; ++k) mb = fmaxf(mb, gm[k]);
    float rb = 0.f, zb = 0.f;
#pragma unroll 8
    for (int k = 0; k < 32; ++k) {
      float scl = expf(gm[k] - mb);
      rb += gr[k][t] * scl;
      zb += gz[k] * scl;
    }
    part[blockIdx.x * 68 + t] = rb;
    if (t == 0) { part[blockIdx.x * 68 + 64] = mb; part[blockIdx.x * 68 + 65] = zb; }
  }
}

// ---------------- Set2Set finish: reduce partials -> q_star -> LSTM(next) -> hv ----------------
// mode 0: boot (no reduce; LSTM from q*=0), 1: mid step, 2: final (write out, no LSTM)
__global__ __launch_bounds__(256) void k_attfin(const float* __restrict__ part,
                                                const float* __restrict__ gw, const float* __restrict__ gb,
                                                const float* __restrict__ gms,
                                                const float* __restrict__ sums, const float* __restrict__ sumsq,
                                                const float* __restrict__ Wih, const float* __restrict__ Whh,
                                                const float* __restrict__ bih, const float* __restrict__ bhh,
                                                float* __restrict__ sm, float* __restrict__ out, int mode) {
  __shared__ float hsL[64], cL[64], qsL[128], gL[256], red[256], sf[NB_ATT], rr4[4][64];
  int t = threadIdx.x, lane = t & 63, w = t >> 6;
  if (t < 64) { hsL[t] = sm[SM_HS + t]; cL[t] = sm[SM_C + t]; }
  __syncthreads();
  if (mode > 0) {
    float mv = part[t * 68 + 64];
    red[t] = mv; __syncthreads();
    for (int s = 128; s; s >>= 1) { if (t < s) red[t] = fmaxf(red[t], red[t + s]); __syncthreads(); }
    float mg = red[0];
    __syncthreads();
    float sc_ = expf(mv - mg);
    sf[t] = sc_;
    red[t] = part[t * 68 + 65] * sc_; __syncthreads();
    for (int s = 128; s; s >>= 1) { if (t < s) red[t] += red[t + s]; __syncthreads(); }
    float zg = red[0];
    __syncthreads();
    float racc = 0.f;
#pragma unroll 8
    for (int j = 0; j < 64; ++j) {
      int bk = 4 * j + w;
      racc += part[bk * 68 + lane] * sf[bk];
    }
    rr4[w][lane] = racc;
    __syncthreads();
    if (t < 64) {
      float rg = rr4[0][t] + rr4[1][t] + rr4[2][t] + rr4[3][t];
      float sc, sh;
      gn_affine(t, gw, gb, gms, sums, sumsq, sc, sh);
      float rr = sc * (rg / zg) + sh;
      qsL[t] = hsL[t]; qsL[64 + t] = rr;
      if (mode == 2) { out[t] = hsL[t]; out[64 + t] = rr; }
    }
  } else {
    if (t < 64) { qsL[t] = 0.f; qsL[64 + t] = 0.f; hsL[t] = 0.f; cL[t] = 0.f; }
  }
  __syncthreads();
  if (mode == 2) return;
  float g = bih[t] + bhh[t];
#pragma unroll 16
  for (int k = 0; k < 128; ++k) g += qsL[k] * Wih[t * 128 + k];
#pragma unroll 16
  for (int k = 0; k < 64; ++k) g += hsL[k] * Whh[t * 64 + k];
  gL[t] = g;
  __syncthreads();
  if (t < 64) {
    float ig = 1.f / (1.f + expf(-gL[t]));
    float fg = 1.f / (1.f + expf(-gL[64 + t]));
    float gg = tanhf(gL[128 + t]);
    float og = 1.f / (1.f + expf(-gL[192 + t]));
    float c = fg * cL[t] + ig * gg;
    float hsn = og * tanhf(c);
    sm[SM_C + t] = c;
    sm[SM_HS + t] = hsn;
    float sc, sh;
    gn_affine(t, gw, gb, gms, sums, sumsq, sc, sh);
    sm[SM_HV + t] = sc * hsn;
    red[t] = sh * hsn;
  }
  __syncthreads();
  if (t == 0) {
    float s = 0.f;
    for (int k = 0; k < 64; ++k) s += red[k];
    sm[SM_EOFF] = s;
  }
}

extern "C" void kernel_launch(void* const* d_in, const int* in_sizes, int n_in,
                              void* d_out, int out_size, void* d_ws, size_t ws_size,
                              hipStream_t stream) {
  const float* x     = (const float*)d_in[0];
  const float* gn0_w = (const float*)d_in[1];
  const float* gn0_b = (const float*)d_in[2];
  const float* gn0_ms= (const float*)d_in[3];
  const float* W1    = (const float*)d_in[4];
  const float* b1    = (const float*)d_in[5];
  const float* a1    = (const float*)d_in[6];
  const float* gn1_w = (const float*)d_in[7];
  const float* gn1_b = (const float*)d_in[8];
  const float* gn1_ms= (const float*)d_in[9];
  const float* W2    = (const float*)d_in[10];
  const float* b2    = (const float*)d_in[11];
  const float* a2    = (const float*)d_in[12];
  const float* gn2_w = (const float*)d_in[13];
  const float* gn2_b = (const float*)d_in[14];
  const float* gn2_ms= (const float*)d_in[15];
  const float* W3    = (const float*)d_in[16];
  const float* b3    = (const float*)d_in[17];
  const float* gn3_w = (const float*)d_in[18];
  const float* gn3_b = (const float*)d_in[19];
  const float* gn3_ms= (const float*)d_in[20];
  const float* Wih   = (const float*)d_in[21];
  const float* Whh   = (const float*)d_in[22];
  const float* bih   = (const float*)d_in[23];
  const float* bhh   = (const float*)d_in[24];
  const int*   eidx  = (const int*)d_in[25];
  const int* esrc = eidx;
  const int* edst = eidx + NE;

  float* sm   = (float*)d_ws;
  float* dinv = sm + OFF_DINV;
  float* h    = sm + OFF_H;
  unsigned* stage = (unsigned*)(sm + OFF_H);   // aliases h; dead before first gather
  uint4* hb4  = (uint4*)(sm + OFF_H);          // aliases h; written only after h is dead
  unsigned* y32 = (unsigned*)(sm + OFF_Y32);
  const uint4* y4 = (const uint4*)y32;
  float* part = sm + OFF_PART;
  int* col    = (int*)(sm + OFF_INT);          // NE
  int* rowptr = col + NE;                      // NPAD (NN+1)
  int* gcursor= rowptr + NPAD;                 // NBUK
  int* boff   = gcursor + 512;                 // NBUK+1
  float* out  = (float*)d_out;

  hipMemsetAsync(sm, 0, SM_COUNT * sizeof(float), stream);

  // CSR build via bucketed counting sort (once)
  k_binit<<<1, 512, 0, stream>>>(gcursor);
  k_bin<<<NTILES, 256, 0, stream>>>(esrc, edst, gcursor, stage);
  k_bscan<<<1, 512, 0, stream>>>(gcursor, boff, rowptr);
  k_bsort<<<NBUK, 256, 0, stream>>>(stage, boff, col, rowptr, dinv);

  k_sums4<<<1024, 256, 0, stream>>>(x, sm + SM_SUMS(0), sm + SM_SUMSQ(0));

  // layer 1
  k_mm<4><<<1024, 256, 0, stream>>>(x, W1, gn0_w, gn0_b, gn0_ms,
                                    sm + SM_SUMS(0), sm + SM_SUMSQ(0), dinv, y32);
  k_gather_fin<true, false><<<2048, 256, 0, stream>>>(y4, rowptr, col, dinv, b1, a1, h, nullptr,
                                                      sm + SM_SUMS(1), sm + SM_SUMSQ(1));
  // layer 2
  k_mm<64><<<1024, 256, 0, stream>>>(h, W2, gn1_w, gn1_b, gn1_ms,
                                     sm + SM_SUMS(1), sm + SM_SUMSQ(1), dinv, y32);
  k_gather_fin<true, false><<<2048, 256, 0, stream>>>(y4, rowptr, col, dinv, b2, a2, h, nullptr,
                                                      sm + SM_SUMS(2), sm + SM_SUMSQ(2));
  // layer 3 (no prelu): writes bf16 h copy only (fp32 h is dead after this k_mm)
  k_mm<64><<<1024, 256, 0, stream>>>(h, W3, gn2_w, gn2_b, gn2_ms,
                                     sm + SM_SUMS(2), sm + SM_SUMSQ(2), dinv, y32);
  k_gather_fin<false, true><<<2048, 256, 0, stream>>>(y4, rowptr, col, dinv, b3, nullptr, nullptr, hb4,
                                                      sm + SM_SUMS(3), sm + SM_SUMSQ(3));

  // Set2Set: boot LSTM (q*=0) + hv, then 3 fused steps
  k_attfin<<<1, 256, 0, stream>>>(part, gn3_w, gn3_b, gn3_ms,
                                  sm + SM_SUMS(3), sm + SM_SUMSQ(3),
                                  Wih, Whh, bih, bhh, sm, nullptr, 0);
  for (int s = 0; s < 3; ++s) {
    k_att<<<NB_ATT, 256, 0, stream>>>(hb4, sm, part);
    k_attfin<<<1, 256, 0, stream>>>(part, gn3_w, gn3_b, gn3_ms,
                                    sm + SM_SUMS(3), sm + SM_SUMSQ(3),
                                    Wih, Whh, bih, bhh, sm,
                                    (s == 2) ? out : nullptr, (s == 2) ? 2 : 1);
  }
}